// Round 15
// baseline (283.188 us; speedup 1.0000x reference)
//
#include <hip/hip_runtime.h>

#define HD 128          // hidden dim (== DIN)
#define DDOC 512
#define TOUT 32
#define RB 16           // rows per block in gemm
#define SCANB 256
#define PROWS 64        // rows per block in pooling
#define NSLICE 256      // edge slices == CSR-build blocks
#define HBLK 1024       // threads per CSR-build block
#define MAXW 15008      // LDS words for packed u16 node counters (>= N/2)
constexpr float NEG_SLOPE = 0.2f;

// ---------- bf16 helpers ----------
__device__ __forceinline__ unsigned short f2bf(float f) {
    unsigned int b = __float_as_uint(f);
    b += 0x7fffu + ((b >> 16) & 1u);     // round-to-nearest-even
    return (unsigned short)(b >> 16);
}
__device__ __forceinline__ float bflo2f(unsigned int u) { return __uint_as_float(u << 16); }
__device__ __forceinline__ float bfhi2f(unsigned int u) { return __uint_as_float(u & 0xffff0000u); }
__device__ __forceinline__ unsigned int pk2bf(float lo, float hi) {
    return (unsigned int)f2bf(lo) | ((unsigned int)f2bf(hi) << 16);
}

// ---------- prep: zero pooled, compute gptr via binary search ----------
__global__ void k_prep(const int* __restrict__ batch, int* __restrict__ gptr,
                       float* __restrict__ pooled, int n, int G) {
    int i = blockIdx.x * blockDim.x + threadIdx.x;
    if (i < G * HD) pooled[i] = 0.f;
    if (i <= G) {
        if (i == G) { gptr[G] = n; }
        else {
            int lo = 0, hi = n;
            while (lo < hi) {
                int mid = (lo + hi) >> 1;
                if (batch[mid] < i) lo = mid + 1; else hi = mid;
            }
            gptr[i] = lo;
        }
    }
}

// ---------- tiled GEMM + fused alpha: h = x@W (bf16 out), alpha = h.a (fp32) ----------
template <bool BF16IN>
__global__ void k_gemm_alpha(const void* __restrict__ xin, const float* __restrict__ W,
                             const float* __restrict__ av_s, const float* __restrict__ av_d,
                             unsigned short* __restrict__ h, float* __restrict__ alp_s,
                             float* __restrict__ alp_d, int n) {
    int row0 = blockIdx.x * RB;
    int t = threadIdx.x;            // 0..255
    int c = t & (HD - 1);
    int rg = t >> 7;                // 0: rows 0-7, 1: rows 8-15

    __shared__ float xs[RB][HD];
    {   // staging: each thread loads 8 contiguous channels of one row
        int idx = t * 8;
        int r = idx >> 7, k = idx & (HD - 1);
        int row = row0 + r;
        if (row < n) {
            if (BF16IN) {
                const unsigned short* xb = (const unsigned short*)xin;
                uint4 v = *(const uint4*)&xb[(size_t)row * HD + k];
                xs[r][k + 0] = bflo2f(v.x); xs[r][k + 1] = bfhi2f(v.x);
                xs[r][k + 2] = bflo2f(v.y); xs[r][k + 3] = bfhi2f(v.y);
                xs[r][k + 4] = bflo2f(v.z); xs[r][k + 5] = bfhi2f(v.z);
                xs[r][k + 6] = bflo2f(v.w); xs[r][k + 7] = bfhi2f(v.w);
            } else {
                const float* xf = (const float*)xin;
                float4 v0 = *(const float4*)&xf[(size_t)row * HD + k];
                float4 v1 = *(const float4*)&xf[(size_t)row * HD + k + 4];
                xs[r][k + 0] = v0.x; xs[r][k + 1] = v0.y;
                xs[r][k + 2] = v0.z; xs[r][k + 3] = v0.w;
                xs[r][k + 4] = v1.x; xs[r][k + 5] = v1.y;
                xs[r][k + 6] = v1.z; xs[r][k + 7] = v1.w;
            }
        } else {
#pragma unroll
            for (int j = 0; j < 8; ++j) xs[r][k + j] = 0.f;
        }
    }
    __syncthreads();

    float acc[8] = {0.f, 0.f, 0.f, 0.f, 0.f, 0.f, 0.f, 0.f};
    for (int k = 0; k < HD; ++k) {
        float w = W[k * HD + c];
#pragma unroll
        for (int r = 0; r < 8; ++r) acc[r] = fmaf(xs[rg * 8 + r][k], w, acc[r]);
    }
#pragma unroll
    for (int r = 0; r < 8; ++r) {
        int row = row0 + rg * 8 + r;
        if (row < n) h[row * HD + c] = f2bf(acc[r]);
    }

    float as = av_s[c], ad = av_d[c];
    __shared__ float redS[4][8], redD[4][8];
    int wave = t >> 6, lane = t & 63;
#pragma unroll
    for (int r = 0; r < 8; ++r) {
        float vs = acc[r] * as;
        float vd = acc[r] * ad;
#pragma unroll
        for (int off = 32; off > 0; off >>= 1) {
            vs += __shfl_xor(vs, off);
            vd += __shfl_xor(vd, off);
        }
        if (lane == 0) { redS[wave][r] = vs; redD[wave][r] = vd; }
    }
    __syncthreads();
    if (t < RB) {
        int w0 = (t < 8) ? 0 : 2;
        int rr = t & 7;
        int row = row0 + t;
        if (row < n) {
            alp_s[row] = redS[w0][rr] + redS[w0 + 1][rr];
            alp_d[row] = redD[w0][rr] + redD[w0 + 1][rr];
        }
    }
}

// ---------- CSR build: per-slice LDS histogram, u16-packed (zero global atomics) ----------
// block s histograms edges [s*slice_sz, (s+1)*slice_sz) over ALL nodes in LDS.
__global__ void k_hist_lds(const int* __restrict__ ei, int E, int Etot, int n,
                           int slice_sz, unsigned short* __restrict__ cnt,
                           unsigned short* __restrict__ rank) {
    __shared__ unsigned int hh[MAXW];
    int s = blockIdx.x;
    int t = threadIdx.x;
    int nW = (n + 1) >> 1;
    for (int i = t; i < nW; i += HBLK) hh[i] = 0u;
    __syncthreads();
    int lo = s * slice_sz;
    int hi = lo + slice_sz; if (hi > Etot) hi = Etot;
    for (int j = lo + t; j < hi; j += HBLK) {
        int d = (j < E) ? ei[E + j] : (j - E);
        int sh = (d & 1) * 16;
        unsigned int old = atomicAdd(&hh[d >> 1], 1u << sh);
        rank[j] = (unsigned short)((old >> sh) & 0xffffu);
    }
    __syncthreads();
    unsigned int* crow = (unsigned int*)(cnt + (size_t)s * n);
    for (int i = t; i < nW; i += HBLK) crow[i] = hh[i];
}

// ---------- per-node exclusive offsets across slices (in-place) + deg + block sums ----------
__global__ void k_nodeoff_scan(unsigned short* __restrict__ cnt, int* __restrict__ deg,
                               int* __restrict__ bsum, int nPairs) {
    int t = threadIdx.x;
    int p = blockIdx.x * SCANB + t;      // node pair index
    int run0 = 0, run1 = 0;
    if (p < nPairs) {
        unsigned int* base = (unsigned int*)cnt + p;   // u32 view: [NSLICE][nPairs]
#pragma unroll 8
        for (int s = 0; s < NSLICE; ++s) {
            unsigned int v = base[(size_t)s * nPairs];
            base[(size_t)s * nPairs] = (unsigned int)run0 | ((unsigned int)run1 << 16);
            run0 += (int)(v & 0xffffu);
            run1 += (int)(v >> 16);
        }
        deg[2 * p] = run0;
        deg[2 * p + 1] = run1;
    }
    int v = run0 + run1;
#pragma unroll
    for (int off = 32; off > 0; off >>= 1) v += __shfl_xor(v, off);
    __shared__ int red[4];
    if ((t & 63) == 0) red[t >> 6] = v;
    __syncthreads();
    if (t == 0) bsum[blockIdx.x] = red[0] + red[1] + red[2] + red[3];
}

__global__ void k_scan_bsum(int* __restrict__ bsum, int nb) {
    __shared__ int part[SCANB];
    int t = threadIdx.x;
    int v = (t < nb) ? bsum[t] : 0;
    part[t] = v;
    __syncthreads();
    for (int off = 1; off < SCANB; off <<= 1) {
        int u = (t >= off) ? part[t - off] : 0;
        __syncthreads();
        part[t] += u;
        __syncthreads();
    }
    if (t < nb) bsum[t] = part[t] - v;   // exclusive
}

__global__ void k_scan_final(const int* __restrict__ deg, const int* __restrict__ bsum,
                             int* __restrict__ ptr, int nPairs, int n, int total) {
    __shared__ int part[SCANB];
    int t = threadIdx.x;
    int p = blockIdx.x * SCANB + t;
    int v0 = 0, v1 = 0;
    if (p < nPairs) { v0 = deg[2 * p]; v1 = deg[2 * p + 1]; }
    int pv = v0 + v1;
    part[t] = pv;
    __syncthreads();
    for (int off = 1; off < SCANB; off <<= 1) {
        int u = (t >= off) ? part[t - off] : 0;
        __syncthreads();
        part[t] += u;
        __syncthreads();
    }
    if (p < nPairs) {
        int excl = bsum[blockIdx.x] + part[t] - pv;
        ptr[2 * p] = excl;
        ptr[2 * p + 1] = excl + v0;
        if (p == nPairs - 1) ptr[n] = total;
    }
}

// ---------- fill: LDS-preloaded slice offsets, atomic-free ----------
__global__ void k_fill_lds(const int* __restrict__ ei, int E, int Etot, int n,
                           int slice_sz, const int* __restrict__ ptr,
                           const unsigned short* __restrict__ cnt,
                           const unsigned short* __restrict__ rank,
                           int* __restrict__ col) {
    __shared__ unsigned int offs[MAXW];
    int s = blockIdx.x;
    int t = threadIdx.x;
    int nW = (n + 1) >> 1;
    const unsigned int* orow = (const unsigned int*)(cnt + (size_t)s * n);
    for (int i = t; i < nW; i += HBLK) offs[i] = orow[i];
    __syncthreads();
    const unsigned short* o16 = (const unsigned short*)offs;
    int lo = s * slice_sz;
    int hi = lo + slice_sz; if (hi > Etot) hi = Etot;
    for (int j = lo + t; j < hi; j += HBLK) {
        int src, d;
        if (j < E) { src = ei[j]; d = ei[E + j]; } else { src = d = j - E; }
        col[ptr[d] + (int)o16[d] + (int)rank[j]] = src;
    }
}

// ---------- fused GAT aggregation (h bf16 in, A bf16 out, quarter-wave phase B) ----------
__global__ void k_gat_gather(const int* __restrict__ ptr, const int* __restrict__ col,
                             const unsigned short* __restrict__ h,
                             const float* __restrict__ alp_s, const float* __restrict__ alp_d,
                             const float* __restrict__ bias, float* __restrict__ wbuf,
                             unsigned short* __restrict__ out, int n) {
    int node = blockIdx.x * 4 + (threadIdx.x >> 6);
    if (node >= n) return;
    int lane = threadIdx.x & 63;
    int beg = ptr[node], end = ptr[node + 1];
    int deg = end - beg;
    float ad = alp_d[node];

    // ---- phase A: e, wave-max, exp, denom ----
    float m = -3.4e38f;
    float e_reg = 0.f;
    int   c_reg = 0;
    if (deg <= 64) {
        if (lane < deg) {
            int s = col[beg + lane];
            c_reg = s;
            float e = alp_s[s] + ad;
            e = e > 0.f ? e : NEG_SLOPE * e;
            e_reg = e;
            m = e;
        }
    } else {
        for (int j = beg + lane; j < end; j += 64) {
            int s = col[j];
            float e = alp_s[s] + ad;
            e = e > 0.f ? e : NEG_SLOPE * e;
            wbuf[j] = e;
            m = fmaxf(m, e);
        }
    }
#pragma unroll
    for (int off = 32; off > 0; off >>= 1) m = fmaxf(m, __shfl_xor(m, off));

    float den = 0.f;
    if (deg <= 64) {
        float ee = (lane < deg) ? __expf(e_reg - m) : 0.f;
        e_reg = ee;
        den = ee;
    } else {
        for (int j = beg + lane; j < end; j += 64) {
            float ee = __expf(wbuf[j] - m);
            wbuf[j] = ee;
            den += ee;
        }
    }
#pragma unroll
    for (int off = 32; off > 0; off >>= 1) den += __shfl_xor(den, off);

    // ---- phase B: 4 edges/iter; quarter-wave (16 lanes) per edge ----
    const uint4* __restrict__ h4 = (const uint4*)h;
    int q = lane >> 4;              // 0..3: which edge of the group
    int l16 = lane & 15;
    float accA[4] = {0.f, 0.f, 0.f, 0.f};
    float accB[4] = {0.f, 0.f, 0.f, 0.f};
    if (deg <= 64) {
        for (int j = beg; j < end; j += 4) {
            int idx = j + q;
            int t = (idx < end) ? (idx - beg) : (deg - 1);
            int s = __shfl(c_reg, t);
            float w = __shfl(e_reg, t);
            if (idx >= end) w = 0.f;
            uint4 hv = h4[(size_t)s * 16 + l16];
            accA[0] = fmaf(w, bflo2f(hv.x), accA[0]);
            accA[1] = fmaf(w, bfhi2f(hv.x), accA[1]);
            accA[2] = fmaf(w, bflo2f(hv.y), accA[2]);
            accA[3] = fmaf(w, bfhi2f(hv.y), accA[3]);
            accB[0] = fmaf(w, bflo2f(hv.z), accB[0]);
            accB[1] = fmaf(w, bfhi2f(hv.z), accB[1]);
            accB[2] = fmaf(w, bflo2f(hv.w), accB[2]);
            accB[3] = fmaf(w, bfhi2f(hv.w), accB[3]);
        }
    } else {
        for (int j = beg; j < end; j += 4) {
            int idx = j + q;
            int ii = (idx < end) ? idx : (end - 1);
            int s = col[ii];
            float w = (idx < end) ? wbuf[ii] : 0.f;
            uint4 hv = h4[(size_t)s * 16 + l16];
            accA[0] = fmaf(w, bflo2f(hv.x), accA[0]);
            accA[1] = fmaf(w, bfhi2f(hv.x), accA[1]);
            accA[2] = fmaf(w, bflo2f(hv.y), accA[2]);
            accA[3] = fmaf(w, bfhi2f(hv.y), accA[3]);
            accB[0] = fmaf(w, bflo2f(hv.z), accB[0]);
            accB[1] = fmaf(w, bfhi2f(hv.z), accB[1]);
            accB[2] = fmaf(w, bflo2f(hv.w), accB[2]);
            accB[3] = fmaf(w, bfhi2f(hv.w), accB[3]);
        }
    }
#pragma unroll
    for (int r = 0; r < 4; ++r) {
        accA[r] += __shfl_xor(accA[r], 16);
        accA[r] += __shfl_xor(accA[r], 32);
        accB[r] += __shfl_xor(accB[r], 16);
        accB[r] += __shfl_xor(accB[r], 32);
    }

    if (q == 0) {
        float inv = 1.f / den;
        const float4* b4 = (const float4*)bias;
        float4 bb0 = b4[l16 * 2];
        float4 bb1 = b4[l16 * 2 + 1];
        float o[8];
        o[0] = fmaf(accA[0], inv, bb0.x); o[1] = fmaf(accA[1], inv, bb0.y);
        o[2] = fmaf(accA[2], inv, bb0.z); o[3] = fmaf(accA[3], inv, bb0.w);
        o[4] = fmaf(accB[0], inv, bb1.x); o[5] = fmaf(accB[1], inv, bb1.y);
        o[6] = fmaf(accB[2], inv, bb1.z); o[7] = fmaf(accB[3], inv, bb1.w);
#pragma unroll
        for (int r = 0; r < 8; ++r) o[r] = o[r] > 0.f ? o[r] : 0.f;
        uint4 pk;
        pk.x = pk2bf(o[0], o[1]); pk.y = pk2bf(o[2], o[3]);
        pk.z = pk2bf(o[4], o[5]); pk.w = pk2bf(o[6], o[7]);
        ((uint4*)out)[(size_t)node * 16 + l16] = pk;
    }
}

// ---------- parallel mean pool over bf16 A: partials, flush on graph change ----------
__global__ void k_pool_part(const unsigned short* __restrict__ x, const int* __restrict__ batch,
                            float* __restrict__ pooled, int n) {
    int r0 = blockIdx.x * PROWS;
    int t = threadIdx.x;            // 0..255
    int cp = t & 63;                // channel pair (2*cp, 2*cp+1)
    int rg = t >> 6;                // 0..3
    int rend = r0 + PROWS; if (rend > n) rend = n;
    float a0 = 0.f, a1 = 0.f;
    int curg = -1;
    for (int r = r0 + rg; r < rend; r += 4) {
        int g = batch[r];
        if (g != curg) {
            if (curg >= 0) {
                atomicAdd(&pooled[curg * HD + 2 * cp], a0);
                atomicAdd(&pooled[curg * HD + 2 * cp + 1], a1);
            }
            curg = g;
            a0 = a1 = 0.f;
        }
        unsigned int u = ((const unsigned int*)(x + (size_t)r * HD))[cp];
        a0 += bflo2f(u);
        a1 += bfhi2f(u);
    }
    if (curg >= 0) {
        atomicAdd(&pooled[curg * HD + 2 * cp], a0);
        atomicAdd(&pooled[curg * HD + 2 * cp + 1], a1);
    }
}

// ---------- fused doc-embedding + mean-div + heads (one block per graph) ----------
__global__ void k_head(const float* __restrict__ pooled, const int* __restrict__ gptr,
                       const float* __restrict__ doc, const float* __restrict__ Wd,
                       const float* __restrict__ bd,
                       const float* __restrict__ Wt, const float* __restrict__ bt,
                       const float* __restrict__ Wm, const float* __restrict__ bm,
                       float* __restrict__ out_task, float* __restrict__ out_time) {
    int g = blockIdx.x;
    int t = threadIdx.x;            // 0..127
    __shared__ float ds[DDOC];
    __shared__ float z[2 * HD];
    for (int k = t; k < DDOC; k += HD) ds[k] = doc[g * DDOC + k];
    float cnt = (float)(gptr[g + 1] - gptr[g]);
    cnt = cnt < 1.f ? 1.f : cnt;
    z[t] = pooled[g * HD + t] / cnt;
    __syncthreads();
    float acc = bd[t];
    for (int k = 0; k < DDOC; ++k) acc = fmaf(ds[k], Wd[k * HD + t], acc);
    z[HD + t] = acc > 0.f ? acc : 0.f;
    __syncthreads();
    if (t < TOUT) {
        float a = bt[t];
        for (int k = 0; k < 2 * HD; ++k) a = fmaf(z[k], Wt[k * TOUT + t], a);
        out_task[g * TOUT + t] = a;
    } else if (t == TOUT) {
        float a = bm[0];
        for (int k = 0; k < 2 * HD; ++k) a = fmaf(z[k], Wm[k], a);
        out_time[g] = a;
    }
}

extern "C" void kernel_launch(void* const* d_in, const int* in_sizes, int n_in,
                              void* d_out, int out_size, void* d_ws, size_t ws_size,
                              hipStream_t stream) {
    const float* x0    = (const float*)d_in[0];
    const int*   ei    = (const int*)d_in[1];
    const int*   batch = (const int*)d_in[2];
    const float* doc   = (const float*)d_in[3];
    const float* W[3]   = {(const float*)d_in[4],  (const float*)d_in[8],  (const float*)d_in[12]};
    const float* a_s[3] = {(const float*)d_in[5],  (const float*)d_in[9],  (const float*)d_in[13]};
    const float* a_d[3] = {(const float*)d_in[6],  (const float*)d_in[10], (const float*)d_in[14]};
    const float* b[3]   = {(const float*)d_in[7],  (const float*)d_in[11], (const float*)d_in[15]};
    const float* Wdoc  = (const float*)d_in[16];
    const float* bdoc  = (const float*)d_in[17];
    const float* Wtask = (const float*)d_in[18];
    const float* btask = (const float*)d_in[19];
    const float* Wtime = (const float*)d_in[20];
    const float* btime = (const float*)d_in[21];

    const int N    = in_sizes[2];
    const int E    = in_sizes[1] / 2;
    const int Etot = E + N;
    const int G    = in_sizes[3] / DDOC;
    const int nPairs = N >> 1;                 // N is even (30000)

    // workspace layout
    float* ws = (float*)d_ws;
    unsigned short* A  = (unsigned short*)ws; ws += (size_t)N * HD / 2;  // layer output (bf16)
    unsigned short* Hb = (unsigned short*)ws; ws += (size_t)N * HD / 2;  // h (bf16)
    float* alp_s  = ws; ws += N;
    float* alp_d  = ws; ws += N;
    float* wbuf   = ws; ws += Etot;             // fallback softmax weights (deg>64)
    float* pooled = ws; ws += (size_t)G * HD;
    unsigned short* cnt  = (unsigned short*)ws; ws += (size_t)NSLICE * N / 2;  // u16 [NSLICE][N]
    unsigned short* rank = (unsigned short*)ws; ws += (Etot + 1) / 2;          // u16 [Etot]
    int* deg    = (int*)ws; ws += N;
    int* ptr    = (int*)ws; ws += N + 1;
    int* gptr   = (int*)ws; ws += G + 1;
    int* bsum   = (int*)ws; ws += SCANB;
    int* col    = (int*)ws; ws += Etot;

    float* out_task = (float*)d_out;
    float* out_time = out_task + (size_t)G * TOUT;

    const int thr = 256;
    const int slice_sz = (Etot + NSLICE - 1) / NSLICE;    // 2461
    const int pBlocks = (nPairs + SCANB - 1) / SCANB;     // 59

    // ---- prep (zero pooled, gptr) + CSR build (zero global atomics) ----
    k_prep<<<(G * HD + thr - 1) / thr, thr, 0, stream>>>(batch, gptr, pooled, N, G);
    k_hist_lds<<<NSLICE, HBLK, 0, stream>>>(ei, E, Etot, N, slice_sz, cnt, rank);
    k_nodeoff_scan<<<pBlocks, SCANB, 0, stream>>>(cnt, deg, bsum, nPairs);
    k_scan_bsum<<<1, SCANB, 0, stream>>>(bsum, pBlocks);
    k_scan_final<<<pBlocks, SCANB, 0, stream>>>(deg, bsum, ptr, nPairs, N, Etot);
    k_fill_lds<<<NSLICE, HBLK, 0, stream>>>(ei, E, Etot, N, slice_sz, ptr, cnt, rank, col);

    // ---- 3 GAT layers ----
    const int gBlocks = (N + RB - 1) / RB;
    const int aBlocks = (N + 3) / 4;
    k_gemm_alpha<false><<<gBlocks, thr, 0, stream>>>(x0, W[0], a_s[0], a_d[0],
                                                     Hb, alp_s, alp_d, N);
    k_gat_gather<<<aBlocks, thr, 0, stream>>>(ptr, col, Hb, alp_s, alp_d, b[0], wbuf, A, N);
    for (int l = 1; l < 3; ++l) {
        k_gemm_alpha<true><<<gBlocks, thr, 0, stream>>>(A, W[l], a_s[l], a_d[l],
                                                        Hb, alp_s, alp_d, N);
        k_gat_gather<<<aBlocks, thr, 0, stream>>>(ptr, col, Hb, alp_s, alp_d, b[l], wbuf, A, N);
    }

    // ---- global mean pool (parallel partials; divide fused into head) ----
    k_pool_part<<<(N + PROWS - 1) / PROWS, thr, 0, stream>>>(A, batch, pooled, N);

    // ---- fused doc embedding + heads ----
    k_head<<<G, HD, 0, stream>>>(pooled, gptr, doc, Wdoc, bdoc,
                                 Wtask, btask, Wtime, btime, out_task, out_time);
}

// Round 16
// 205.243 us; speedup vs baseline: 1.3798x; 1.3798x over previous
//
#include <hip/hip_runtime.h>

#define HD 128          // hidden dim (== DIN)
#define DDOC 512
#define TOUT 32
#define SCANB 256
#define PROWS 64        // rows per block in pooling
constexpr float NEG_SLOPE = 0.2f;

typedef __attribute__((ext_vector_type(8))) short short8;
typedef __attribute__((ext_vector_type(4))) float f32x4;

// ---------- bf16 helpers ----------
__device__ __forceinline__ unsigned short f2bf(float f) {
    unsigned int b = __float_as_uint(f);
    b += 0x7fffu + ((b >> 16) & 1u);     // round-to-nearest-even
    return (unsigned short)(b >> 16);
}
__device__ __forceinline__ float bflo2f(unsigned int u) { return __uint_as_float(u << 16); }
__device__ __forceinline__ float bfhi2f(unsigned int u) { return __uint_as_float(u & 0xffff0000u); }
__device__ __forceinline__ unsigned int pk2bf(float lo, float hi) {
    return (unsigned int)f2bf(lo) | ((unsigned int)f2bf(hi) << 16);
}

// ---------- prep (grid-stride): zero pooled/deg, gptr, x0->bf16, W->frag-packed bf16 ----------
__global__ void k_prep(const int* __restrict__ batch, int* __restrict__ gptr,
                       float* __restrict__ pooled, int* __restrict__ deg,
                       const float* __restrict__ x0, unsigned short* __restrict__ x0b,
                       const float* __restrict__ W0, const float* __restrict__ W1,
                       const float* __restrict__ W2, unsigned short* __restrict__ Wb,
                       int n, int G, int total) {
    int stride = gridDim.x * blockDim.x;
    int t0 = blockIdx.x * blockDim.x + threadIdx.x;
    for (int i = t0; i < total; i += stride) x0b[i] = f2bf(x0[i]);
    for (int i = t0; i < G * HD; i += stride) pooled[i] = 0.f;
    for (int i = t0; i < n; i += stride) deg[i] = 0;
    for (int i = t0; i < 3 * 16384; i += stride) {
        int l = i >> 14, idx = i & 16383;
        int j = idx & 7, lane = (idx >> 3) & 63, tile = idx >> 9;  // tile = ks*8+ct
        int ks = tile >> 3, ct = tile & 7;
        int k = ks * 32 + (lane >> 4) * 8 + j;
        int c = ct * 16 + (lane & 15);
        const float* Wl = (l == 0) ? W0 : ((l == 1) ? W1 : W2);
        Wb[i] = f2bf(Wl[k * HD + c]);
    }
    for (int i = t0; i <= G; i += stride) {
        if (i == G) { gptr[G] = n; }
        else {
            int lo = 0, hi = n;
            while (lo < hi) {
                int mid = (lo + hi) >> 1;
                if (batch[mid] < i) lo = mid + 1; else hi = mid;
            }
            gptr[i] = lo;
        }
    }
}

// ---------- MFMA GEMM + fused alpha: h = x@W (bf16 in/out), alpha = h.a ----------
// block = 256 thr = 4 waves; 64 rows/block (16/wave), full 128 cols; no LDS.
__global__ void k_gemm_mfma(const unsigned short* __restrict__ x,   // bf16 [n][HD]
                            const unsigned short* __restrict__ Wb,  // frag-packed bf16
                            const float* __restrict__ av_s, const float* __restrict__ av_d,
                            unsigned short* __restrict__ h, float* __restrict__ alp_s,
                            float* __restrict__ alp_d, int n) {
    int wave = threadIdx.x >> 6;
    int lane = threadIdx.x & 63;
    int l16 = lane & 15, lk = lane >> 4;
    int r0 = blockIdx.x * 64 + wave * 16;

    // A fragments for 4 K-steps: row = r0+l16, k = ks*32 + lk*8 + j (contiguous 16B)
    int arow = r0 + l16;
    if (arow >= n) arow = n - 1;
    const short8* ap = (const short8*)(x + (size_t)arow * HD);
    short8 a[4];
#pragma unroll
    for (int ks = 0; ks < 4; ++ks) a[ks] = ap[ks * 4 + lk];

    f32x4 acc[8];
#pragma unroll
    for (int ct = 0; ct < 8; ++ct) acc[ct] = (f32x4){0.f, 0.f, 0.f, 0.f};

    const short8* wp = (const short8*)Wb;
#pragma unroll
    for (int ct = 0; ct < 8; ++ct) {
#pragma unroll
        for (int ks = 0; ks < 4; ++ks) {
            short8 b = wp[(ks * 8 + ct) * 64 + lane];
            acc[ct] = __builtin_amdgcn_mfma_f32_16x16x32_bf16(a[ks], b, acc[ct], 0, 0, 0);
        }
    }

    // C/D layout: col = ct*16 + l16, row = r0 + lk*4 + i
    float ps[4] = {0.f, 0.f, 0.f, 0.f}, pd[4] = {0.f, 0.f, 0.f, 0.f};
#pragma unroll
    for (int ct = 0; ct < 8; ++ct) {
        int c = ct * 16 + l16;
        float as_ = av_s[c], ad_ = av_d[c];
#pragma unroll
        for (int i = 0; i < 4; ++i) {
            int row = r0 + lk * 4 + i;
            float v = acc[ct][i];
            if (row < n) h[(size_t)row * HD + c] = f2bf(v);
            ps[i] = fmaf(v, as_, ps[i]);
            pd[i] = fmaf(v, ad_, pd[i]);
        }
    }
    // reduce alpha partials across the 16 lanes of each row group
#pragma unroll
    for (int i = 0; i < 4; ++i) {
#pragma unroll
        for (int off = 1; off < 16; off <<= 1) {
            ps[i] += __shfl_xor(ps[i], off);
            pd[i] += __shfl_xor(pd[i], off);
        }
    }
    if (l16 == 0) {
#pragma unroll
        for (int i = 0; i < 4; ++i) {
            int row = r0 + lk * 4 + i;
            if (row < n) { alp_s[row] = ps[i]; alp_d[row] = pd[i]; }
        }
    }
}

// ---------- CSR build: hist captures per-edge rank (one atomic pass total) ----------
__global__ void k_hist(const int* __restrict__ ei, int E, int Etot,
                       int* __restrict__ deg, int* __restrict__ rank) {
    int i = blockIdx.x * blockDim.x + threadIdx.x;
    if (i >= Etot) return;
    int d = (i < E) ? ei[E + i] : (i - E);
    rank[i] = atomicAdd(&deg[d], 1);
}

// ---------- 3-phase device-wide exclusive scan of deg -> ptr ----------
__global__ void k_scan_part(const int* __restrict__ deg, int* __restrict__ bsum, int n) {
    int t = threadIdx.x;
    int i = blockIdx.x * SCANB + t;
    int v = (i < n) ? deg[i] : 0;
#pragma unroll
    for (int off = 32; off > 0; off >>= 1) v += __shfl_xor(v, off);
    __shared__ int red[4];
    if ((t & 63) == 0) red[t >> 6] = v;
    __syncthreads();
    if (t == 0) bsum[blockIdx.x] = red[0] + red[1] + red[2] + red[3];
}

__global__ void k_scan_bsum(int* __restrict__ bsum, int nb) {
    __shared__ int part[SCANB];
    int t = threadIdx.x;
    int v = (t < nb) ? bsum[t] : 0;
    part[t] = v;
    __syncthreads();
    for (int off = 1; off < SCANB; off <<= 1) {
        int u = (t >= off) ? part[t - off] : 0;
        __syncthreads();
        part[t] += u;
        __syncthreads();
    }
    if (t < nb) bsum[t] = part[t] - v;   // exclusive
}

__global__ void k_scan_final(const int* __restrict__ deg, const int* __restrict__ bsum,
                             int* __restrict__ ptr, int n, int total) {
    __shared__ int part[SCANB];
    int t = threadIdx.x;
    int i = blockIdx.x * SCANB + t;
    int v = (i < n) ? deg[i] : 0;
    part[t] = v;
    __syncthreads();
    for (int off = 1; off < SCANB; off <<= 1) {
        int u = (t >= off) ? part[t - off] : 0;
        __syncthreads();
        part[t] += u;
        __syncthreads();
    }
    if (i < n) ptr[i] = bsum[blockIdx.x] + part[t] - v;
    if (i == n - 1) ptr[n] = total;
}

// ---------- fill: atomic-free, pos = ptr[d] + rank[i] ----------
__global__ void k_fill(const int* __restrict__ ei, int E, int Etot,
                       const int* __restrict__ ptr, const int* __restrict__ rank,
                       int* __restrict__ col) {
    int i = blockIdx.x * blockDim.x + threadIdx.x;
    if (i >= Etot) return;
    int s, d;
    if (i < E) { s = ei[i]; d = ei[E + i]; } else { s = d = i - E; }
    col[ptr[d] + rank[i]] = s;
}

// ---------- fused GAT aggregation (h bf16 in, A bf16 out, quarter-wave phase B) ----------
__global__ void k_gat_gather(const int* __restrict__ ptr, const int* __restrict__ col,
                             const unsigned short* __restrict__ h,
                             const float* __restrict__ alp_s, const float* __restrict__ alp_d,
                             const float* __restrict__ bias, float* __restrict__ wbuf,
                             unsigned short* __restrict__ out, int n) {
    int node = blockIdx.x * 4 + (threadIdx.x >> 6);
    if (node >= n) return;
    int lane = threadIdx.x & 63;
    int beg = ptr[node], end = ptr[node + 1];
    int deg = end - beg;
    float ad = alp_d[node];

    // ---- phase A: e, wave-max, exp, denom ----
    float m = -3.4e38f;
    float e_reg = 0.f;
    int   c_reg = 0;
    if (deg <= 64) {
        if (lane < deg) {
            int s = col[beg + lane];
            c_reg = s;
            float e = alp_s[s] + ad;
            e = e > 0.f ? e : NEG_SLOPE * e;
            e_reg = e;
            m = e;
        }
    } else {
        for (int j = beg + lane; j < end; j += 64) {
            int s = col[j];
            float e = alp_s[s] + ad;
            e = e > 0.f ? e : NEG_SLOPE * e;
            wbuf[j] = e;
            m = fmaxf(m, e);
        }
    }
#pragma unroll
    for (int off = 32; off > 0; off >>= 1) m = fmaxf(m, __shfl_xor(m, off));

    float den = 0.f;
    if (deg <= 64) {
        float ee = (lane < deg) ? __expf(e_reg - m) : 0.f;
        e_reg = ee;
        den = ee;
    } else {
        for (int j = beg + lane; j < end; j += 64) {
            float ee = __expf(wbuf[j] - m);
            wbuf[j] = ee;
            den += ee;
        }
    }
#pragma unroll
    for (int off = 32; off > 0; off >>= 1) den += __shfl_xor(den, off);

    // ---- phase B: 4 edges/iter; quarter-wave (16 lanes) per edge ----
    const uint4* __restrict__ h4 = (const uint4*)h;
    int q = lane >> 4;
    int l16 = lane & 15;
    float accA[4] = {0.f, 0.f, 0.f, 0.f};
    float accB[4] = {0.f, 0.f, 0.f, 0.f};
    if (deg <= 64) {
        for (int j = beg; j < end; j += 4) {
            int idx = j + q;
            int t = (idx < end) ? (idx - beg) : (deg - 1);
            int s = __shfl(c_reg, t);
            float w = __shfl(e_reg, t);
            if (idx >= end) w = 0.f;
            uint4 hv = h4[(size_t)s * 16 + l16];
            accA[0] = fmaf(w, bflo2f(hv.x), accA[0]);
            accA[1] = fmaf(w, bfhi2f(hv.x), accA[1]);
            accA[2] = fmaf(w, bflo2f(hv.y), accA[2]);
            accA[3] = fmaf(w, bfhi2f(hv.y), accA[3]);
            accB[0] = fmaf(w, bflo2f(hv.z), accB[0]);
            accB[1] = fmaf(w, bfhi2f(hv.z), accB[1]);
            accB[2] = fmaf(w, bflo2f(hv.w), accB[2]);
            accB[3] = fmaf(w, bfhi2f(hv.w), accB[3]);
        }
    } else {
        for (int j = beg; j < end; j += 4) {
            int idx = j + q;
            int ii = (idx < end) ? idx : (end - 1);
            int s = col[ii];
            float w = (idx < end) ? wbuf[ii] : 0.f;
            uint4 hv = h4[(size_t)s * 16 + l16];
            accA[0] = fmaf(w, bflo2f(hv.x), accA[0]);
            accA[1] = fmaf(w, bfhi2f(hv.x), accA[1]);
            accA[2] = fmaf(w, bflo2f(hv.y), accA[2]);
            accA[3] = fmaf(w, bfhi2f(hv.y), accA[3]);
            accB[0] = fmaf(w, bflo2f(hv.z), accB[0]);
            accB[1] = fmaf(w, bfhi2f(hv.z), accB[1]);
            accB[2] = fmaf(w, bflo2f(hv.w), accB[2]);
            accB[3] = fmaf(w, bfhi2f(hv.w), accB[3]);
        }
    }
#pragma unroll
    for (int r = 0; r < 4; ++r) {
        accA[r] += __shfl_xor(accA[r], 16);
        accA[r] += __shfl_xor(accA[r], 32);
        accB[r] += __shfl_xor(accB[r], 16);
        accB[r] += __shfl_xor(accB[r], 32);
    }

    if (q == 0) {
        float inv = 1.f / den;
        const float4* b4 = (const float4*)bias;
        float4 bb0 = b4[l16 * 2];
        float4 bb1 = b4[l16 * 2 + 1];
        float o[8];
        o[0] = fmaf(accA[0], inv, bb0.x); o[1] = fmaf(accA[1], inv, bb0.y);
        o[2] = fmaf(accA[2], inv, bb0.z); o[3] = fmaf(accA[3], inv, bb0.w);
        o[4] = fmaf(accB[0], inv, bb1.x); o[5] = fmaf(accB[1], inv, bb1.y);
        o[6] = fmaf(accB[2], inv, bb1.z); o[7] = fmaf(accB[3], inv, bb1.w);
#pragma unroll
        for (int r = 0; r < 8; ++r) o[r] = o[r] > 0.f ? o[r] : 0.f;
        uint4 pk;
        pk.x = pk2bf(o[0], o[1]); pk.y = pk2bf(o[2], o[3]);
        pk.z = pk2bf(o[4], o[5]); pk.w = pk2bf(o[6], o[7]);
        ((uint4*)out)[(size_t)node * 16 + l16] = pk;
    }
}

// ---------- parallel mean pool over bf16 A: partials, flush on graph change ----------
__global__ void k_pool_part(const unsigned short* __restrict__ x, const int* __restrict__ batch,
                            float* __restrict__ pooled, int n) {
    int r0 = blockIdx.x * PROWS;
    int t = threadIdx.x;
    int cp = t & 63;
    int rg = t >> 6;
    int rend = r0 + PROWS; if (rend > n) rend = n;
    float a0 = 0.f, a1 = 0.f;
    int curg = -1;
    for (int r = r0 + rg; r < rend; r += 4) {
        int g = batch[r];
        if (g != curg) {
            if (curg >= 0) {
                atomicAdd(&pooled[curg * HD + 2 * cp], a0);
                atomicAdd(&pooled[curg * HD + 2 * cp + 1], a1);
            }
            curg = g;
            a0 = a1 = 0.f;
        }
        unsigned int u = ((const unsigned int*)(x + (size_t)r * HD))[cp];
        a0 += bflo2f(u);
        a1 += bfhi2f(u);
    }
    if (curg >= 0) {
        atomicAdd(&pooled[curg * HD + 2 * cp], a0);
        atomicAdd(&pooled[curg * HD + 2 * cp + 1], a1);
    }
}

// ---------- fused doc-embedding + mean-div + heads (one block per graph) ----------
__global__ void k_head(const float* __restrict__ pooled, const int* __restrict__ gptr,
                       const float* __restrict__ doc, const float* __restrict__ Wd,
                       const float* __restrict__ bd,
                       const float* __restrict__ Wt, const float* __restrict__ bt,
                       const float* __restrict__ Wm, const float* __restrict__ bm,
                       float* __restrict__ out_task, float* __restrict__ out_time) {
    int g = blockIdx.x;
    int t = threadIdx.x;            // 0..127
    __shared__ float ds[DDOC];
    __shared__ float z[2 * HD];
    for (int k = t; k < DDOC; k += HD) ds[k] = doc[g * DDOC + k];
    float cnt = (float)(gptr[g + 1] - gptr[g]);
    cnt = cnt < 1.f ? 1.f : cnt;
    z[t] = pooled[g * HD + t] / cnt;
    __syncthreads();
    float acc = bd[t];
    for (int k = 0; k < DDOC; ++k) acc = fmaf(ds[k], Wd[k * HD + t], acc);
    z[HD + t] = acc > 0.f ? acc : 0.f;
    __syncthreads();
    if (t < TOUT) {
        float a = bt[t];
        for (int k = 0; k < 2 * HD; ++k) a = fmaf(z[k], Wt[k * TOUT + t], a);
        out_task[g * TOUT + t] = a;
    } else if (t == TOUT) {
        float a = bm[0];
        for (int k = 0; k < 2 * HD; ++k) a = fmaf(z[k], Wm[k], a);
        out_time[g] = a;
    }
}

extern "C" void kernel_launch(void* const* d_in, const int* in_sizes, int n_in,
                              void* d_out, int out_size, void* d_ws, size_t ws_size,
                              hipStream_t stream) {
    const float* x0    = (const float*)d_in[0];
    const int*   ei    = (const int*)d_in[1];
    const int*   batch = (const int*)d_in[2];
    const float* doc   = (const float*)d_in[3];
    const float* W[3]   = {(const float*)d_in[4],  (const float*)d_in[8],  (const float*)d_in[12]};
    const float* a_s[3] = {(const float*)d_in[5],  (const float*)d_in[9],  (const float*)d_in[13]};
    const float* a_d[3] = {(const float*)d_in[6],  (const float*)d_in[10], (const float*)d_in[14]};
    const float* b[3]   = {(const float*)d_in[7],  (const float*)d_in[11], (const float*)d_in[15]};
    const float* Wdoc  = (const float*)d_in[16];
    const float* bdoc  = (const float*)d_in[17];
    const float* Wtask = (const float*)d_in[18];
    const float* btask = (const float*)d_in[19];
    const float* Wtime = (const float*)d_in[20];
    const float* btime = (const float*)d_in[21];

    const int N    = in_sizes[2];
    const int E    = in_sizes[1] / 2;
    const int Etot = E + N;
    const int G    = in_sizes[3] / DDOC;

    // workspace layout (float-slot accounting)
    float* ws = (float*)d_ws;
    unsigned short* A  = (unsigned short*)ws; ws += (size_t)N * HD / 2;  // x0b then layer output (bf16)
    unsigned short* Hb = (unsigned short*)ws; ws += (size_t)N * HD / 2;  // h (bf16)
    unsigned short* Wb = (unsigned short*)ws; ws += (3 * 16384) / 2;     // frag-packed W (bf16)
    float* alp_s  = ws; ws += N;
    float* alp_d  = ws; ws += N;
    float* wbuf   = ws; ws += Etot;             // fallback softmax weights (deg>64)
    float* pooled = ws; ws += (size_t)G * HD;
    int* deg    = (int*)ws; ws += N;
    int* rank   = (int*)ws; ws += Etot;
    int* ptr    = (int*)ws; ws += N + 1;
    int* gptr   = (int*)ws; ws += G + 1;
    int* bsum   = (int*)ws; ws += SCANB;
    int* col    = (int*)ws; ws += Etot;

    float* out_task = (float*)d_out;
    float* out_time = out_task + (size_t)G * TOUT;

    const int thr = 256;
    const int eBlocks = (Etot + thr - 1) / thr;
    const int sBlocks = (N + SCANB - 1) / SCANB;

    // ---- prep: zeros, gptr, x0->bf16 (into A), W->frag-packed bf16 ----
    k_prep<<<2048, thr, 0, stream>>>(batch, gptr, pooled, deg, x0, A,
                                     W[0], W[1], W[2], Wb, N, G, N * HD);

    // ---- CSR build (round-10 structure: one atomic pass + free fill) ----
    k_hist<<<eBlocks, thr, 0, stream>>>(ei, E, Etot, deg, rank);
    k_scan_part<<<sBlocks, SCANB, 0, stream>>>(deg, bsum, N);
    k_scan_bsum<<<1, SCANB, 0, stream>>>(bsum, sBlocks);
    k_scan_final<<<sBlocks, SCANB, 0, stream>>>(deg, bsum, ptr, N, Etot);
    k_fill<<<eBlocks, thr, 0, stream>>>(ei, E, Etot, ptr, rank, col);

    // ---- 3 GAT layers (MFMA gemm; A is bf16 x0 for layer 1, then layer output) ----
    const int mBlocks = (N + 63) / 64;
    const int aBlocks = (N + 3) / 4;
    for (int l = 0; l < 3; ++l) {
        k_gemm_mfma<<<mBlocks, thr, 0, stream>>>(A, Wb + l * 16384, a_s[l], a_d[l],
                                                 Hb, alp_s, alp_d, N);
        k_gat_gather<<<aBlocks, thr, 0, stream>>>(ptr, col, Hb, alp_s, alp_d, b[l],
                                                  wbuf, A, N);
    }

    // ---- global mean pool (parallel partials; divide fused into head) ----
    k_pool_part<<<(N + PROWS - 1) / PROWS, thr, 0, stream>>>(A, batch, pooled, N);

    // ---- fused doc embedding + heads ----
    k_head<<<G, HD, 0, stream>>>(pooled, gptr, doc, Wdoc, bdoc,
                                 Wtask, btask, Wtime, btime, out_task, out_time);
}

// Round 17
// 199.206 us; speedup vs baseline: 1.4216x; 1.0303x over previous
//
#include <hip/hip_runtime.h>

#define HD 128          // hidden dim (== DIN)
#define DDOC 512
#define TOUT 32
#define SCANB 256
#define PROWS 64        // rows per block in pooling
constexpr float NEG_SLOPE = 0.2f;

typedef __attribute__((ext_vector_type(8))) short short8;
typedef __attribute__((ext_vector_type(4))) float f32x4;

// ---------- bf16 helpers ----------
__device__ __forceinline__ unsigned short f2bf(float f) {
    unsigned int b = __float_as_uint(f);
    b += 0x7fffu + ((b >> 16) & 1u);     // round-to-nearest-even
    return (unsigned short)(b >> 16);
}
__device__ __forceinline__ float bflo2f(unsigned int u) { return __uint_as_float(u << 16); }
__device__ __forceinline__ float bfhi2f(unsigned int u) { return __uint_as_float(u & 0xffff0000u); }
__device__ __forceinline__ unsigned int pk2bf(float lo, float hi) {
    return (unsigned int)f2bf(lo) | ((unsigned int)f2bf(hi) << 16);
}

// ---------- prep (grid-stride): zero pooled/deg, gptr, x0->bf16, W->frag-packed bf16 ----------
__global__ void k_prep(const int* __restrict__ batch, int* __restrict__ gptr,
                       float* __restrict__ pooled, int* __restrict__ deg,
                       const float* __restrict__ x0, unsigned short* __restrict__ x0b,
                       const float* __restrict__ W0, const float* __restrict__ W1,
                       const float* __restrict__ W2, unsigned short* __restrict__ Wb,
                       int n, int G, int total) {
    int stride = gridDim.x * blockDim.x;
    int t0 = blockIdx.x * blockDim.x + threadIdx.x;
    for (int i = t0; i < total; i += stride) x0b[i] = f2bf(x0[i]);
    for (int i = t0; i < G * HD; i += stride) pooled[i] = 0.f;
    for (int i = t0; i < n; i += stride) deg[i] = 0;
    for (int i = t0; i < 3 * 16384; i += stride) {
        int l = i >> 14, idx = i & 16383;
        int j = idx & 7, lane = (idx >> 3) & 63, tile = idx >> 9;  // tile = ks*8+ct
        int ks = tile >> 3, ct = tile & 7;
        int k = ks * 32 + (lane >> 4) * 8 + j;
        int c = ct * 16 + (lane & 15);
        const float* Wl = (l == 0) ? W0 : ((l == 1) ? W1 : W2);
        Wb[i] = f2bf(Wl[k * HD + c]);
    }
    for (int i = t0; i <= G; i += stride) {
        if (i == G) { gptr[G] = n; }
        else {
            int lo = 0, hi = n;
            while (lo < hi) {
                int mid = (lo + hi) >> 1;
                if (batch[mid] < i) lo = mid + 1; else hi = mid;
            }
            gptr[i] = lo;
        }
    }
}

// ---------- MFMA GEMM + fused alpha: h = x@W (bf16 in/out), alpha = h.a ----------
__global__ void k_gemm_mfma(const unsigned short* __restrict__ x,   // bf16 [n][HD]
                            const unsigned short* __restrict__ Wb,  // frag-packed bf16
                            const float* __restrict__ av_s, const float* __restrict__ av_d,
                            unsigned short* __restrict__ h, float* __restrict__ alp_s,
                            float* __restrict__ alp_d, int n) {
    int wave = threadIdx.x >> 6;
    int lane = threadIdx.x & 63;
    int l16 = lane & 15, lk = lane >> 4;
    int r0 = blockIdx.x * 64 + wave * 16;

    int arow = r0 + l16;
    if (arow >= n) arow = n - 1;
    const short8* ap = (const short8*)(x + (size_t)arow * HD);
    short8 a[4];
#pragma unroll
    for (int ks = 0; ks < 4; ++ks) a[ks] = ap[ks * 4 + lk];

    f32x4 acc[8];
#pragma unroll
    for (int ct = 0; ct < 8; ++ct) acc[ct] = (f32x4){0.f, 0.f, 0.f, 0.f};

    const short8* wp = (const short8*)Wb;
#pragma unroll
    for (int ct = 0; ct < 8; ++ct) {
#pragma unroll
        for (int ks = 0; ks < 4; ++ks) {
            short8 b = wp[(ks * 8 + ct) * 64 + lane];
            acc[ct] = __builtin_amdgcn_mfma_f32_16x16x32_bf16(a[ks], b, acc[ct], 0, 0, 0);
        }
    }

    // C/D layout: col = ct*16 + l16, row = r0 + lk*4 + i
    float ps[4] = {0.f, 0.f, 0.f, 0.f}, pd[4] = {0.f, 0.f, 0.f, 0.f};
#pragma unroll
    for (int ct = 0; ct < 8; ++ct) {
        int c = ct * 16 + l16;
        float as_ = av_s[c], ad_ = av_d[c];
#pragma unroll
        for (int i = 0; i < 4; ++i) {
            int row = r0 + lk * 4 + i;
            float v = acc[ct][i];
            if (row < n) h[(size_t)row * HD + c] = f2bf(v);
            ps[i] = fmaf(v, as_, ps[i]);
            pd[i] = fmaf(v, ad_, pd[i]);
        }
    }
#pragma unroll
    for (int i = 0; i < 4; ++i) {
#pragma unroll
        for (int off = 1; off < 16; off <<= 1) {
            ps[i] += __shfl_xor(ps[i], off);
            pd[i] += __shfl_xor(pd[i], off);
        }
    }
    if (l16 == 0) {
#pragma unroll
        for (int i = 0; i < 4; ++i) {
            int row = r0 + lk * 4 + i;
            if (row < n) { alp_s[row] = ps[i]; alp_d[row] = pd[i]; }
        }
    }
}

// ---------- CSR build: hist captures per-edge rank (one atomic pass total) ----------
__global__ void k_hist(const int* __restrict__ ei, int E, int Etot,
                       int* __restrict__ deg, int* __restrict__ rank) {
    int i = blockIdx.x * blockDim.x + threadIdx.x;
    if (i >= Etot) return;
    int d = (i < E) ? ei[E + i] : (i - E);
    rank[i] = atomicAdd(&deg[d], 1);
}

// ---------- 3-phase device-wide exclusive scan of deg -> ptr ----------
__global__ void k_scan_part(const int* __restrict__ deg, int* __restrict__ bsum, int n) {
    int t = threadIdx.x;
    int i = blockIdx.x * SCANB + t;
    int v = (i < n) ? deg[i] : 0;
#pragma unroll
    for (int off = 32; off > 0; off >>= 1) v += __shfl_xor(v, off);
    __shared__ int red[4];
    if ((t & 63) == 0) red[t >> 6] = v;
    __syncthreads();
    if (t == 0) bsum[blockIdx.x] = red[0] + red[1] + red[2] + red[3];
}

__global__ void k_scan_bsum(int* __restrict__ bsum, int nb) {
    __shared__ int part[SCANB];
    int t = threadIdx.x;
    int v = (t < nb) ? bsum[t] : 0;
    part[t] = v;
    __syncthreads();
    for (int off = 1; off < SCANB; off <<= 1) {
        int u = (t >= off) ? part[t - off] : 0;
        __syncthreads();
        part[t] += u;
        __syncthreads();
    }
    if (t < nb) bsum[t] = part[t] - v;   // exclusive
}

__global__ void k_scan_final(const int* __restrict__ deg, const int* __restrict__ bsum,
                             int* __restrict__ ptr, int n, int total) {
    __shared__ int part[SCANB];
    int t = threadIdx.x;
    int i = blockIdx.x * SCANB + t;
    int v = (i < n) ? deg[i] : 0;
    part[t] = v;
    __syncthreads();
    for (int off = 1; off < SCANB; off <<= 1) {
        int u = (t >= off) ? part[t - off] : 0;
        __syncthreads();
        part[t] += u;
        __syncthreads();
    }
    if (i < n) ptr[i] = bsum[blockIdx.x] + part[t] - v;
    if (i == n - 1) ptr[n] = total;
}

// ---------- fill: atomic-free, pos = ptr[d] + rank[i] ----------
__global__ void k_fill(const int* __restrict__ ei, int E, int Etot,
                       const int* __restrict__ ptr, const int* __restrict__ rank,
                       int* __restrict__ col) {
    int i = blockIdx.x * blockDim.x + threadIdx.x;
    if (i >= Etot) return;
    int s, d;
    if (i < E) { s = ei[i]; d = ei[E + i]; } else { s = d = i - E; }
    col[ptr[d] + rank[i]] = s;
}

// ---------- fused GAT aggregation (h bf16 in, A bf16 out) ----------
// phase B: 8 edges/iter, two independent row loads per lane for MLP
__global__ void k_gat_gather(const int* __restrict__ ptr, const int* __restrict__ col,
                             const unsigned short* __restrict__ h,
                             const float* __restrict__ alp_s, const float* __restrict__ alp_d,
                             const float* __restrict__ bias, float* __restrict__ wbuf,
                             unsigned short* __restrict__ out, int n) {
    int node = blockIdx.x * 4 + (threadIdx.x >> 6);
    if (node >= n) return;
    int lane = threadIdx.x & 63;
    int beg = ptr[node], end = ptr[node + 1];
    int deg = end - beg;
    float ad = alp_d[node];

    // ---- phase A: e, wave-max, exp, denom ----
    float m = -3.4e38f;
    float e_reg = 0.f;
    int   c_reg = 0;
    if (deg <= 64) {
        if (lane < deg) {
            int s = col[beg + lane];
            c_reg = s;
            float e = alp_s[s] + ad;
            e = e > 0.f ? e : NEG_SLOPE * e;
            e_reg = e;
            m = e;
        }
    } else {
        for (int j = beg + lane; j < end; j += 64) {
            int s = col[j];
            float e = alp_s[s] + ad;
            e = e > 0.f ? e : NEG_SLOPE * e;
            wbuf[j] = e;
            m = fmaxf(m, e);
        }
    }
#pragma unroll
    for (int off = 32; off > 0; off >>= 1) m = fmaxf(m, __shfl_xor(m, off));

    float den = 0.f;
    if (deg <= 64) {
        float ee = (lane < deg) ? __expf(e_reg - m) : 0.f;
        e_reg = ee;
        den = ee;
    } else {
        for (int j = beg + lane; j < end; j += 64) {
            float ee = __expf(wbuf[j] - m);
            wbuf[j] = ee;
            den += ee;
        }
    }
#pragma unroll
    for (int off = 32; off > 0; off >>= 1) den += __shfl_xor(den, off);

    // ---- phase B ----
    const uint4* __restrict__ h4 = (const uint4*)h;
    int q = lane >> 4;
    int l16 = lane & 15;
    float accA[4] = {0.f, 0.f, 0.f, 0.f};
    float accB[4] = {0.f, 0.f, 0.f, 0.f};
    if (deg <= 64) {
        // 8 edges per iteration: quarter-wave handles edges j+q and j+4+q
#pragma unroll 2
        for (int j = beg; j < end; j += 8) {
            int idx0 = j + q;
            int idx1 = j + 4 + q;
            int t0 = (idx0 < end) ? (idx0 - beg) : (deg - 1);
            int t1 = (idx1 < end) ? (idx1 - beg) : (deg - 1);
            int s0 = __shfl(c_reg, t0);
            int s1 = __shfl(c_reg, t1);
            float w0 = __shfl(e_reg, t0);
            float w1 = __shfl(e_reg, t1);
            if (idx0 >= end) w0 = 0.f;
            if (idx1 >= end) w1 = 0.f;
            uint4 hv0 = h4[(size_t)s0 * 16 + l16];
            uint4 hv1 = h4[(size_t)s1 * 16 + l16];
            accA[0] = fmaf(w0, bflo2f(hv0.x), accA[0]);
            accA[1] = fmaf(w0, bfhi2f(hv0.x), accA[1]);
            accA[2] = fmaf(w0, bflo2f(hv0.y), accA[2]);
            accA[3] = fmaf(w0, bfhi2f(hv0.y), accA[3]);
            accB[0] = fmaf(w0, bflo2f(hv0.z), accB[0]);
            accB[1] = fmaf(w0, bfhi2f(hv0.z), accB[1]);
            accB[2] = fmaf(w0, bflo2f(hv0.w), accB[2]);
            accB[3] = fmaf(w0, bfhi2f(hv0.w), accB[3]);
            accA[0] = fmaf(w1, bflo2f(hv1.x), accA[0]);
            accA[1] = fmaf(w1, bfhi2f(hv1.x), accA[1]);
            accA[2] = fmaf(w1, bflo2f(hv1.y), accA[2]);
            accA[3] = fmaf(w1, bfhi2f(hv1.y), accA[3]);
            accB[0] = fmaf(w1, bflo2f(hv1.z), accB[0]);
            accB[1] = fmaf(w1, bfhi2f(hv1.z), accB[1]);
            accB[2] = fmaf(w1, bflo2f(hv1.w), accB[2]);
            accB[3] = fmaf(w1, bfhi2f(hv1.w), accB[3]);
        }
    } else {
        for (int j = beg; j < end; j += 4) {
            int idx = j + q;
            int ii = (idx < end) ? idx : (end - 1);
            int s = col[ii];
            float w = (idx < end) ? wbuf[ii] : 0.f;
            uint4 hv = h4[(size_t)s * 16 + l16];
            accA[0] = fmaf(w, bflo2f(hv.x), accA[0]);
            accA[1] = fmaf(w, bfhi2f(hv.x), accA[1]);
            accA[2] = fmaf(w, bflo2f(hv.y), accA[2]);
            accA[3] = fmaf(w, bfhi2f(hv.y), accA[3]);
            accB[0] = fmaf(w, bflo2f(hv.z), accB[0]);
            accB[1] = fmaf(w, bfhi2f(hv.z), accB[1]);
            accB[2] = fmaf(w, bflo2f(hv.w), accB[2]);
            accB[3] = fmaf(w, bfhi2f(hv.w), accB[3]);
        }
    }
#pragma unroll
    for (int r = 0; r < 4; ++r) {
        accA[r] += __shfl_xor(accA[r], 16);
        accA[r] += __shfl_xor(accA[r], 32);
        accB[r] += __shfl_xor(accB[r], 16);
        accB[r] += __shfl_xor(accB[r], 32);
    }

    if (q == 0) {
        float inv = 1.f / den;
        const float4* b4 = (const float4*)bias;
        float4 bb0 = b4[l16 * 2];
        float4 bb1 = b4[l16 * 2 + 1];
        float o[8];
        o[0] = fmaf(accA[0], inv, bb0.x); o[1] = fmaf(accA[1], inv, bb0.y);
        o[2] = fmaf(accA[2], inv, bb0.z); o[3] = fmaf(accA[3], inv, bb0.w);
        o[4] = fmaf(accB[0], inv, bb1.x); o[5] = fmaf(accB[1], inv, bb1.y);
        o[6] = fmaf(accB[2], inv, bb1.z); o[7] = fmaf(accB[3], inv, bb1.w);
#pragma unroll
        for (int r = 0; r < 8; ++r) o[r] = o[r] > 0.f ? o[r] : 0.f;
        uint4 pk;
        pk.x = pk2bf(o[0], o[1]); pk.y = pk2bf(o[2], o[3]);
        pk.z = pk2bf(o[4], o[5]); pk.w = pk2bf(o[6], o[7]);
        ((uint4*)out)[(size_t)node * 16 + l16] = pk;
    }
}

// ---------- parallel mean pool over bf16 A: partials, flush on graph change ----------
__global__ void k_pool_part(const unsigned short* __restrict__ x, const int* __restrict__ batch,
                            float* __restrict__ pooled, int n) {
    int r0 = blockIdx.x * PROWS;
    int t = threadIdx.x;
    int cp = t & 63;
    int rg = t >> 6;
    int rend = r0 + PROWS; if (rend > n) rend = n;
    float a0 = 0.f, a1 = 0.f;
    int curg = -1;
    for (int r = r0 + rg; r < rend; r += 4) {
        int g = batch[r];
        if (g != curg) {
            if (curg >= 0) {
                atomicAdd(&pooled[curg * HD + 2 * cp], a0);
                atomicAdd(&pooled[curg * HD + 2 * cp + 1], a1);
            }
            curg = g;
            a0 = a1 = 0.f;
        }
        unsigned int u = ((const unsigned int*)(x + (size_t)r * HD))[cp];
        a0 += bflo2f(u);
        a1 += bfhi2f(u);
    }
    if (curg >= 0) {
        atomicAdd(&pooled[curg * HD + 2 * cp], a0);
        atomicAdd(&pooled[curg * HD + 2 * cp + 1], a1);
    }
}

// ---------- fused doc-embedding + mean-div + heads (one block per graph) ----------
__global__ void k_head(const float* __restrict__ pooled, const int* __restrict__ gptr,
                       const float* __restrict__ doc, const float* __restrict__ Wd,
                       const float* __restrict__ bd,
                       const float* __restrict__ Wt, const float* __restrict__ bt,
                       const float* __restrict__ Wm, const float* __restrict__ bm,
                       float* __restrict__ out_task, float* __restrict__ out_time) {
    int g = blockIdx.x;
    int t = threadIdx.x;            // 0..127
    __shared__ float ds[DDOC];
    __shared__ float z[2 * HD];
    for (int k = t; k < DDOC; k += HD) ds[k] = doc[g * DDOC + k];
    float cnt = (float)(gptr[g + 1] - gptr[g]);
    cnt = cnt < 1.f ? 1.f : cnt;
    z[t] = pooled[g * HD + t] / cnt;
    __syncthreads();
    float acc = bd[t];
    for (int k = 0; k < DDOC; ++k) acc = fmaf(ds[k], Wd[k * HD + t], acc);
    z[HD + t] = acc > 0.f ? acc : 0.f;
    __syncthreads();
    if (t < TOUT) {
        float a = bt[t];
        for (int k = 0; k < 2 * HD; ++k) a = fmaf(z[k], Wt[k * TOUT + t], a);
        out_task[g * TOUT + t] = a;
    } else if (t == TOUT) {
        float a = bm[0];
        for (int k = 0; k < 2 * HD; ++k) a = fmaf(z[k], Wm[k], a);
        out_time[g] = a;
    }
}

extern "C" void kernel_launch(void* const* d_in, const int* in_sizes, int n_in,
                              void* d_out, int out_size, void* d_ws, size_t ws_size,
                              hipStream_t stream) {
    const float* x0    = (const float*)d_in[0];
    const int*   ei    = (const int*)d_in[1];
    const int*   batch = (const int*)d_in[2];
    const float* doc   = (const float*)d_in[3];
    const float* W[3]   = {(const float*)d_in[4],  (const float*)d_in[8],  (const float*)d_in[12]};
    const float* a_s[3] = {(const float*)d_in[5],  (const float*)d_in[9],  (const float*)d_in[13]};
    const float* a_d[3] = {(const float*)d_in[6],  (const float*)d_in[10], (const float*)d_in[14]};
    const float* b[3]   = {(const float*)d_in[7],  (const float*)d_in[11], (const float*)d_in[15]};
    const float* Wdoc  = (const float*)d_in[16];
    const float* bdoc  = (const float*)d_in[17];
    const float* Wtask = (const float*)d_in[18];
    const float* btask = (const float*)d_in[19];
    const float* Wtime = (const float*)d_in[20];
    const float* btime = (const float*)d_in[21];

    const int N    = in_sizes[2];
    const int E    = in_sizes[1] / 2;
    const int Etot = E + N;
    const int G    = in_sizes[3] / DDOC;

    // workspace layout (float-slot accounting)
    float* ws = (float*)d_ws;
    unsigned short* A  = (unsigned short*)ws; ws += (size_t)N * HD / 2;  // x0b then layer output (bf16)
    unsigned short* Hb = (unsigned short*)ws; ws += (size_t)N * HD / 2;  // h (bf16)
    unsigned short* Wb = (unsigned short*)ws; ws += (3 * 16384) / 2;     // frag-packed W (bf16)
    float* alp_s  = ws; ws += N;
    float* alp_d  = ws; ws += N;
    float* wbuf   = ws; ws += Etot;             // fallback softmax weights (deg>64)
    float* pooled = ws; ws += (size_t)G * HD;
    int* deg    = (int*)ws; ws += N;
    int* rank   = (int*)ws; ws += Etot;
    int* ptr    = (int*)ws; ws += N + 1;
    int* gptr   = (int*)ws; ws += G + 1;
    int* bsum   = (int*)ws; ws += SCANB;
    int* col    = (int*)ws; ws += Etot;

    float* out_task = (float*)d_out;
    float* out_time = out_task + (size_t)G * TOUT;

    const int thr = 256;
    const int eBlocks = (Etot + thr - 1) / thr;
    const int sBlocks = (N + SCANB - 1) / SCANB;

    // ---- prep: zeros, gptr, x0->bf16 (into A), W->frag-packed bf16 ----
    k_prep<<<2048, thr, 0, stream>>>(batch, gptr, pooled, deg, x0, A,
                                     W[0], W[1], W[2], Wb, N, G, N * HD);

    // ---- CSR build (one atomic pass + free fill) ----
    k_hist<<<eBlocks, thr, 0, stream>>>(ei, E, Etot, deg, rank);
    k_scan_part<<<sBlocks, SCANB, 0, stream>>>(deg, bsum, N);
    k_scan_bsum<<<1, SCANB, 0, stream>>>(bsum, sBlocks);
    k_scan_final<<<sBlocks, SCANB, 0, stream>>>(deg, bsum, ptr, N, Etot);
    k_fill<<<eBlocks, thr, 0, stream>>>(ei, E, Etot, ptr, rank, col);

    // ---- 3 GAT layers (MFMA gemm; A is bf16 x0 for layer 1, then layer output) ----
    const int mBlocks = (N + 63) / 64;
    const int aBlocks = (N + 3) / 4;
    for (int l = 0; l < 3; ++l) {
        k_gemm_mfma<<<mBlocks, thr, 0, stream>>>(A, Wb + l * 16384, a_s[l], a_d[l],
                                                 Hb, alp_s, alp_d, N);
        k_gat_gather<<<aBlocks, thr, 0, stream>>>(ptr, col, Hb, alp_s, alp_d, b[l],
                                                  wbuf, A, N);
    }

    // ---- global mean pool (parallel partials; divide fused into head) ----
    k_pool_part<<<(N + PROWS - 1) / PROWS, thr, 0, stream>>>(A, batch, pooled, N);

    // ---- fused doc embedding + heads ----
    k_head<<<G, HD, 0, stream>>>(pooled, gptr, doc, Wdoc, bdoc,
                                 Wtask, btask, Wtime, btime, out_task, out_time);
}

// Round 18
// 195.188 us; speedup vs baseline: 1.4509x; 1.0206x over previous
//
#include <hip/hip_runtime.h>

#define HD 128          // hidden dim (== DIN)
#define DDOC 512
#define TOUT 32
#define SCANB 256
#define PROWS 64        // rows per block in pooling
constexpr float NEG_SLOPE = 0.2f;

typedef __attribute__((ext_vector_type(8))) short short8;
typedef __attribute__((ext_vector_type(4))) float f32x4;

// ---------- bf16 helpers ----------
__device__ __forceinline__ unsigned short f2bf(float f) {
    unsigned int b = __float_as_uint(f);
    b += 0x7fffu + ((b >> 16) & 1u);     // round-to-nearest-even
    return (unsigned short)(b >> 16);
}
__device__ __forceinline__ float bflo2f(unsigned int u) { return __uint_as_float(u << 16); }
__device__ __forceinline__ float bfhi2f(unsigned int u) { return __uint_as_float(u & 0xffff0000u); }
__device__ __forceinline__ unsigned int pk2bf(float lo, float hi) {
    return (unsigned int)f2bf(lo) | ((unsigned int)f2bf(hi) << 16);
}

// ---------- prep (grid-stride): zero pooled/deg, gptr, W->frag-packed bf16 ----------
__global__ void k_prep(const int* __restrict__ batch, int* __restrict__ gptr,
                       float* __restrict__ pooled, int* __restrict__ deg,
                       const float* __restrict__ W0, const float* __restrict__ W1,
                       const float* __restrict__ W2, unsigned short* __restrict__ Wb,
                       int n, int G) {
    int stride = gridDim.x * blockDim.x;
    int t0 = blockIdx.x * blockDim.x + threadIdx.x;
    for (int i = t0; i < G * HD; i += stride) pooled[i] = 0.f;
    for (int i = t0; i < n; i += stride) deg[i] = 0;
    for (int i = t0; i < 3 * 16384; i += stride) {
        int l = i >> 14, idx = i & 16383;
        int j = idx & 7, lane = (idx >> 3) & 63, tile = idx >> 9;  // tile = ks*8+ct
        int ks = tile >> 3, ct = tile & 7;
        int k = ks * 32 + (lane >> 4) * 8 + j;
        int c = ct * 16 + (lane & 15);
        const float* Wl = (l == 0) ? W0 : ((l == 1) ? W1 : W2);
        Wb[i] = f2bf(Wl[k * HD + c]);
    }
    for (int i = t0; i <= G; i += stride) {
        if (i == G) { gptr[G] = n; }
        else {
            int lo = 0, hi = n;
            while (lo < hi) {
                int mid = (lo + hi) >> 1;
                if (batch[mid] < i) lo = mid + 1; else hi = mid;
            }
            gptr[i] = lo;
        }
    }
}

// ---------- MFMA GEMM + fused alpha: h = x@W (bf16 out), alpha = h.a ----------
// F32IN: layer 1 reads fp32 node_features directly, converts in-register.
template <bool F32IN>
__global__ void k_gemm_mfma(const void* __restrict__ xin,
                            const unsigned short* __restrict__ Wb,  // frag-packed bf16
                            const float* __restrict__ av_s, const float* __restrict__ av_d,
                            unsigned short* __restrict__ h, float* __restrict__ alp_s,
                            float* __restrict__ alp_d, int n) {
    int wave = threadIdx.x >> 6;
    int lane = threadIdx.x & 63;
    int l16 = lane & 15, lk = lane >> 4;
    int r0 = blockIdx.x * 64 + wave * 16;

    int arow = r0 + l16;
    if (arow >= n) arow = n - 1;
    short8 a[4];
    if (F32IN) {
        const float* xf = (const float*)xin + (size_t)arow * HD;
#pragma unroll
        for (int ks = 0; ks < 4; ++ks) {
            float4 v0 = *(const float4*)&xf[ks * 32 + lk * 8];
            float4 v1 = *(const float4*)&xf[ks * 32 + lk * 8 + 4];
            short8 t;
            t[0] = (short)f2bf(v0.x); t[1] = (short)f2bf(v0.y);
            t[2] = (short)f2bf(v0.z); t[3] = (short)f2bf(v0.w);
            t[4] = (short)f2bf(v1.x); t[5] = (short)f2bf(v1.y);
            t[6] = (short)f2bf(v1.z); t[7] = (short)f2bf(v1.w);
            a[ks] = t;
        }
    } else {
        const short8* ap = (const short8*)((const unsigned short*)xin + (size_t)arow * HD);
#pragma unroll
        for (int ks = 0; ks < 4; ++ks) a[ks] = ap[ks * 4 + lk];
    }

    f32x4 acc[8];
#pragma unroll
    for (int ct = 0; ct < 8; ++ct) acc[ct] = (f32x4){0.f, 0.f, 0.f, 0.f};

    const short8* wp = (const short8*)Wb;
#pragma unroll
    for (int ct = 0; ct < 8; ++ct) {
#pragma unroll
        for (int ks = 0; ks < 4; ++ks) {
            short8 b = wp[(ks * 8 + ct) * 64 + lane];
            acc[ct] = __builtin_amdgcn_mfma_f32_16x16x32_bf16(a[ks], b, acc[ct], 0, 0, 0);
        }
    }

    // C/D layout: col = ct*16 + l16, row = r0 + lk*4 + i
    float ps[4] = {0.f, 0.f, 0.f, 0.f}, pd[4] = {0.f, 0.f, 0.f, 0.f};
#pragma unroll
    for (int ct = 0; ct < 8; ++ct) {
        int c = ct * 16 + l16;
        float as_ = av_s[c], ad_ = av_d[c];
#pragma unroll
        for (int i = 0; i < 4; ++i) {
            int row = r0 + lk * 4 + i;
            float v = acc[ct][i];
            if (row < n) h[(size_t)row * HD + c] = f2bf(v);
            ps[i] = fmaf(v, as_, ps[i]);
            pd[i] = fmaf(v, ad_, pd[i]);
        }
    }
#pragma unroll
    for (int i = 0; i < 4; ++i) {
#pragma unroll
        for (int off = 1; off < 16; off <<= 1) {
            ps[i] += __shfl_xor(ps[i], off);
            pd[i] += __shfl_xor(pd[i], off);
        }
    }
    if (l16 == 0) {
#pragma unroll
        for (int i = 0; i < 4; ++i) {
            int row = r0 + lk * 4 + i;
            if (row < n) { alp_s[row] = ps[i]; alp_d[row] = pd[i]; }
        }
    }
}

// ---------- CSR build: hist captures per-edge rank (one atomic pass total) ----------
__global__ void k_hist(const int* __restrict__ ei, int E, int Etot,
                       int* __restrict__ deg, int* __restrict__ rank) {
    int i = blockIdx.x * blockDim.x + threadIdx.x;
    if (i >= Etot) return;
    int d = (i < E) ? ei[E + i] : (i - E);
    rank[i] = atomicAdd(&deg[d], 1);
}

// ---------- scan: per-block sums, then final pass (bsum scan folded in) ----------
__global__ void k_scan_part(const int* __restrict__ deg, int* __restrict__ bsum, int n) {
    int t = threadIdx.x;
    int i = blockIdx.x * SCANB + t;
    int v = (i < n) ? deg[i] : 0;
#pragma unroll
    for (int off = 32; off > 0; off >>= 1) v += __shfl_xor(v, off);
    __shared__ int red[4];
    if ((t & 63) == 0) red[t >> 6] = v;
    __syncthreads();
    if (t == 0) bsum[blockIdx.x] = red[0] + red[1] + red[2] + red[3];
}

__global__ void k_scan_final(const int* __restrict__ deg, const int* __restrict__ bsum,
                             int* __restrict__ ptr, int n, int total, int nb) {
    __shared__ int bs[SCANB];
    __shared__ int part[SCANB];
    int t = threadIdx.x;
    // every block scans the block sums redundantly (nb <= SCANB)
    int bv = (t < nb) ? bsum[t] : 0;
    bs[t] = bv;
    __syncthreads();
    for (int off = 1; off < SCANB; off <<= 1) {
        int u = (t >= off) ? bs[t - off] : 0;
        __syncthreads();
        bs[t] += u;
        __syncthreads();
    }
    int base = (blockIdx.x == 0) ? 0 : bs[blockIdx.x - 1];

    int i = blockIdx.x * SCANB + t;
    int v = (i < n) ? deg[i] : 0;
    part[t] = v;
    __syncthreads();
    for (int off = 1; off < SCANB; off <<= 1) {
        int u = (t >= off) ? part[t - off] : 0;
        __syncthreads();
        part[t] += u;
        __syncthreads();
    }
    if (i < n) ptr[i] = base + part[t] - v;
    if (i == n - 1) ptr[n] = total;
}

// ---------- fill: atomic-free, pos = ptr[d] + rank[i] ----------
__global__ void k_fill(const int* __restrict__ ei, int E, int Etot,
                       const int* __restrict__ ptr, const int* __restrict__ rank,
                       int* __restrict__ col) {
    int i = blockIdx.x * blockDim.x + threadIdx.x;
    if (i >= Etot) return;
    int s, d;
    if (i < E) { s = ei[i]; d = ei[E + i]; } else { s = d = i - E; }
    col[ptr[d] + rank[i]] = s;
}

// ---------- fused GAT aggregation (h bf16 in, A bf16 out) ----------
__global__ void k_gat_gather(const int* __restrict__ ptr, const int* __restrict__ col,
                             const unsigned short* __restrict__ h,
                             const float* __restrict__ alp_s, const float* __restrict__ alp_d,
                             const float* __restrict__ bias, float* __restrict__ wbuf,
                             unsigned short* __restrict__ out, int n) {
    int node = blockIdx.x * 4 + (threadIdx.x >> 6);
    if (node >= n) return;
    int lane = threadIdx.x & 63;
    int beg = ptr[node], end = ptr[node + 1];
    int deg = end - beg;
    float ad = alp_d[node];

    // ---- phase A: e, wave-max, exp, denom ----
    float m = -3.4e38f;
    float e_reg = 0.f;
    int   c_reg = 0;
    if (deg <= 64) {
        if (lane < deg) {
            int s = col[beg + lane];
            c_reg = s;
            float e = alp_s[s] + ad;
            e = e > 0.f ? e : NEG_SLOPE * e;
            e_reg = e;
            m = e;
        }
    } else {
        for (int j = beg + lane; j < end; j += 64) {
            int s = col[j];
            float e = alp_s[s] + ad;
            e = e > 0.f ? e : NEG_SLOPE * e;
            wbuf[j] = e;
            m = fmaxf(m, e);
        }
    }
#pragma unroll
    for (int off = 32; off > 0; off >>= 1) m = fmaxf(m, __shfl_xor(m, off));

    float den = 0.f;
    if (deg <= 64) {
        float ee = (lane < deg) ? __expf(e_reg - m) : 0.f;
        e_reg = ee;
        den = ee;
    } else {
        for (int j = beg + lane; j < end; j += 64) {
            float ee = __expf(wbuf[j] - m);
            wbuf[j] = ee;
            den += ee;
        }
    }
#pragma unroll
    for (int off = 32; off > 0; off >>= 1) den += __shfl_xor(den, off);

    // ---- phase B: 8 edges/iter, two independent row loads per lane ----
    const uint4* __restrict__ h4 = (const uint4*)h;
    int q = lane >> 4;
    int l16 = lane & 15;
    float accA[4] = {0.f, 0.f, 0.f, 0.f};
    float accB[4] = {0.f, 0.f, 0.f, 0.f};
    if (deg <= 64) {
#pragma unroll 2
        for (int j = beg; j < end; j += 8) {
            int idx0 = j + q;
            int idx1 = j + 4 + q;
            int t0 = (idx0 < end) ? (idx0 - beg) : (deg - 1);
            int t1 = (idx1 < end) ? (idx1 - beg) : (deg - 1);
            int s0 = __shfl(c_reg, t0);
            int s1 = __shfl(c_reg, t1);
            float w0 = __shfl(e_reg, t0);
            float w1 = __shfl(e_reg, t1);
            if (idx0 >= end) w0 = 0.f;
            if (idx1 >= end) w1 = 0.f;
            uint4 hv0 = h4[(size_t)s0 * 16 + l16];
            uint4 hv1 = h4[(size_t)s1 * 16 + l16];
            accA[0] = fmaf(w0, bflo2f(hv0.x), accA[0]);
            accA[1] = fmaf(w0, bfhi2f(hv0.x), accA[1]);
            accA[2] = fmaf(w0, bflo2f(hv0.y), accA[2]);
            accA[3] = fmaf(w0, bfhi2f(hv0.y), accA[3]);
            accB[0] = fmaf(w0, bflo2f(hv0.z), accB[0]);
            accB[1] = fmaf(w0, bfhi2f(hv0.z), accB[1]);
            accB[2] = fmaf(w0, bflo2f(hv0.w), accB[2]);
            accB[3] = fmaf(w0, bfhi2f(hv0.w), accB[3]);
            accA[0] = fmaf(w1, bflo2f(hv1.x), accA[0]);
            accA[1] = fmaf(w1, bfhi2f(hv1.x), accA[1]);
            accA[2] = fmaf(w1, bflo2f(hv1.y), accA[2]);
            accA[3] = fmaf(w1, bfhi2f(hv1.y), accA[3]);
            accB[0] = fmaf(w1, bflo2f(hv1.z), accB[0]);
            accB[1] = fmaf(w1, bfhi2f(hv1.z), accB[1]);
            accB[2] = fmaf(w1, bflo2f(hv1.w), accB[2]);
            accB[3] = fmaf(w1, bfhi2f(hv1.w), accB[3]);
        }
    } else {
        for (int j = beg; j < end; j += 4) {
            int idx = j + q;
            int ii = (idx < end) ? idx : (end - 1);
            int s = col[ii];
            float w = (idx < end) ? wbuf[ii] : 0.f;
            uint4 hv = h4[(size_t)s * 16 + l16];
            accA[0] = fmaf(w, bflo2f(hv.x), accA[0]);
            accA[1] = fmaf(w, bfhi2f(hv.x), accA[1]);
            accA[2] = fmaf(w, bflo2f(hv.y), accA[2]);
            accA[3] = fmaf(w, bfhi2f(hv.y), accA[3]);
            accB[0] = fmaf(w, bflo2f(hv.z), accB[0]);
            accB[1] = fmaf(w, bfhi2f(hv.z), accB[1]);
            accB[2] = fmaf(w, bflo2f(hv.w), accB[2]);
            accB[3] = fmaf(w, bfhi2f(hv.w), accB[3]);
        }
    }
#pragma unroll
    for (int r = 0; r < 4; ++r) {
        accA[r] += __shfl_xor(accA[r], 16);
        accA[r] += __shfl_xor(accA[r], 32);
        accB[r] += __shfl_xor(accB[r], 16);
        accB[r] += __shfl_xor(accB[r], 32);
    }

    if (q == 0) {
        float inv = 1.f / den;
        const float4* b4 = (const float4*)bias;
        float4 bb0 = b4[l16 * 2];
        float4 bb1 = b4[l16 * 2 + 1];
        float o[8];
        o[0] = fmaf(accA[0], inv, bb0.x); o[1] = fmaf(accA[1], inv, bb0.y);
        o[2] = fmaf(accA[2], inv, bb0.z); o[3] = fmaf(accA[3], inv, bb0.w);
        o[4] = fmaf(accB[0], inv, bb1.x); o[5] = fmaf(accB[1], inv, bb1.y);
        o[6] = fmaf(accB[2], inv, bb1.z); o[7] = fmaf(accB[3], inv, bb1.w);
#pragma unroll
        for (int r = 0; r < 8; ++r) o[r] = o[r] > 0.f ? o[r] : 0.f;
        uint4 pk;
        pk.x = pk2bf(o[0], o[1]); pk.y = pk2bf(o[2], o[3]);
        pk.z = pk2bf(o[4], o[5]); pk.w = pk2bf(o[6], o[7]);
        ((uint4*)out)[(size_t)node * 16 + l16] = pk;
    }
}

// ---------- parallel mean pool over bf16 A: partials, flush on graph change ----------
__global__ void k_pool_part(const unsigned short* __restrict__ x, const int* __restrict__ batch,
                            float* __restrict__ pooled, int n) {
    int r0 = blockIdx.x * PROWS;
    int t = threadIdx.x;
    int cp = t & 63;
    int rg = t >> 6;
    int rend = r0 + PROWS; if (rend > n) rend = n;
    float a0 = 0.f, a1 = 0.f;
    int curg = -1;
    for (int r = r0 + rg; r < rend; r += 4) {
        int g = batch[r];
        if (g != curg) {
            if (curg >= 0) {
                atomicAdd(&pooled[curg * HD + 2 * cp], a0);
                atomicAdd(&pooled[curg * HD + 2 * cp + 1], a1);
            }
            curg = g;
            a0 = a1 = 0.f;
        }
        unsigned int u = ((const unsigned int*)(x + (size_t)r * HD))[cp];
        a0 += bflo2f(u);
        a1 += bfhi2f(u);
    }
    if (curg >= 0) {
        atomicAdd(&pooled[curg * HD + 2 * cp], a0);
        atomicAdd(&pooled[curg * HD + 2 * cp + 1], a1);
    }
}

// ---------- fused doc-embedding + mean-div + heads (one block per graph) ----------
__global__ void k_head(const float* __restrict__ pooled, const int* __restrict__ gptr,
                       const float* __restrict__ doc, const float* __restrict__ Wd,
                       const float* __restrict__ bd,
                       const float* __restrict__ Wt, const float* __restrict__ bt,
                       const float* __restrict__ Wm, const float* __restrict__ bm,
                       float* __restrict__ out_task, float* __restrict__ out_time) {
    int g = blockIdx.x;
    int t = threadIdx.x;            // 0..127
    __shared__ float ds[DDOC];
    __shared__ float z[2 * HD];
    for (int k = t; k < DDOC; k += HD) ds[k] = doc[g * DDOC + k];
    float cnt = (float)(gptr[g + 1] - gptr[g]);
    cnt = cnt < 1.f ? 1.f : cnt;
    z[t] = pooled[g * HD + t] / cnt;
    __syncthreads();
    float acc = bd[t];
    for (int k = 0; k < DDOC; ++k) acc = fmaf(ds[k], Wd[k * HD + t], acc);
    z[HD + t] = acc > 0.f ? acc : 0.f;
    __syncthreads();
    if (t < TOUT) {
        float a = bt[t];
        for (int k = 0; k < 2 * HD; ++k) a = fmaf(z[k], Wt[k * TOUT + t], a);
        out_task[g * TOUT + t] = a;
    } else if (t == TOUT) {
        float a = bm[0];
        for (int k = 0; k < 2 * HD; ++k) a = fmaf(z[k], Wm[k], a);
        out_time[g] = a;
    }
}

extern "C" void kernel_launch(void* const* d_in, const int* in_sizes, int n_in,
                              void* d_out, int out_size, void* d_ws, size_t ws_size,
                              hipStream_t stream) {
    const float* x0    = (const float*)d_in[0];
    const int*   ei    = (const int*)d_in[1];
    const int*   batch = (const int*)d_in[2];
    const float* doc   = (const float*)d_in[3];
    const float* W[3]   = {(const float*)d_in[4],  (const float*)d_in[8],  (const float*)d_in[12]};
    const float* a_s[3] = {(const float*)d_in[5],  (const float*)d_in[9],  (const float*)d_in[13]};
    const float* a_d[3] = {(const float*)d_in[6],  (const float*)d_in[10], (const float*)d_in[14]};
    const float* b[3]   = {(const float*)d_in[7],  (const float*)d_in[11], (const float*)d_in[15]};
    const float* Wdoc  = (const float*)d_in[16];
    const float* bdoc  = (const float*)d_in[17];
    const float* Wtask = (const float*)d_in[18];
    const float* btask = (const float*)d_in[19];
    const float* Wtime = (const float*)d_in[20];
    const float* btime = (const float*)d_in[21];

    const int N    = in_sizes[2];
    const int E    = in_sizes[1] / 2;
    const int Etot = E + N;
    const int G    = in_sizes[3] / DDOC;

    // workspace layout (float-slot accounting)
    float* ws = (float*)d_ws;
    unsigned short* A  = (unsigned short*)ws; ws += (size_t)N * HD / 2;  // layer output (bf16)
    unsigned short* Hb = (unsigned short*)ws; ws += (size_t)N * HD / 2;  // h (bf16)
    unsigned short* Wb = (unsigned short*)ws; ws += (3 * 16384) / 2;     // frag-packed W (bf16)
    float* alp_s  = ws; ws += N;
    float* alp_d  = ws; ws += N;
    float* wbuf   = ws; ws += Etot;             // fallback softmax weights (deg>64)
    float* pooled = ws; ws += (size_t)G * HD;
    int* deg    = (int*)ws; ws += N;
    int* rank   = (int*)ws; ws += Etot;
    int* ptr    = (int*)ws; ws += N + 1;
    int* gptr   = (int*)ws; ws += G + 1;
    int* bsum   = (int*)ws; ws += SCANB;
    int* col    = (int*)ws; ws += Etot;

    float* out_task = (float*)d_out;
    float* out_time = out_task + (size_t)G * TOUT;

    const int thr = 256;
    const int eBlocks = (Etot + thr - 1) / thr;
    const int sBlocks = (N + SCANB - 1) / SCANB;   // 118 <= SCANB

    // ---- prep: zeros, gptr, W->frag-packed bf16 ----
    k_prep<<<512, thr, 0, stream>>>(batch, gptr, pooled, deg, W[0], W[1], W[2], Wb, N, G);

    // ---- CSR build (one atomic pass + free fill; bsum scan folded into final) ----
    k_hist<<<eBlocks, thr, 0, stream>>>(ei, E, Etot, deg, rank);
    k_scan_part<<<sBlocks, SCANB, 0, stream>>>(deg, bsum, N);
    k_scan_final<<<sBlocks, SCANB, 0, stream>>>(deg, bsum, ptr, N, Etot, sBlocks);
    k_fill<<<eBlocks, thr, 0, stream>>>(ei, E, Etot, ptr, rank, col);

    // ---- 3 GAT layers (MFMA gemm; layer 1 reads fp32 x0 directly) ----
    const int mBlocks = (N + 63) / 64;
    const int aBlocks = (N + 3) / 4;
    k_gemm_mfma<true><<<mBlocks, thr, 0, stream>>>(x0, Wb, a_s[0], a_d[0],
                                                   Hb, alp_s, alp_d, N);
    k_gat_gather<<<aBlocks, thr, 0, stream>>>(ptr, col, Hb, alp_s, alp_d, b[0], wbuf, A, N);
    for (int l = 1; l < 3; ++l) {
        k_gemm_mfma<false><<<mBlocks, thr, 0, stream>>>(A, Wb + l * 16384, a_s[l], a_d[l],
                                                        Hb, alp_s, alp_d, N);
        k_gat_gather<<<aBlocks, thr, 0, stream>>>(ptr, col, Hb, alp_s, alp_d, b[l],
                                                  wbuf, A, N);
    }

    // ---- global mean pool (parallel partials; divide fused into head) ----
    k_pool_part<<<(N + PROWS - 1) / PROWS, thr, 0, stream>>>(A, batch, pooled, N);

    // ---- fused doc embedding + heads ----
    k_head<<<G, HD, 0, stream>>>(pooled, gptr, doc, Wdoc, bdoc,
                                 Wtask, btask, Wtime, btime, out_task, out_time);
}